// Round 9
// baseline (178.781 us; speedup 1.0000x reference)
//
#include <hip/hip_runtime.h>
#include <hip/hip_bf16.h>

// GraphAttentionLayer: B=8,N=1024,FIN=E=OUT=128,NH=8,HD=16. f32 in/out.
// R34: vs R33 (157.58us): (1) mfma_out FUSED into flash via ticket counter:
// after ob stores (+syncthreads => vmcnt drained) each block does release
// threadfence + atomicAdd(ticket); the LAST 64 arrivals (ticket>=448) spin
// relaxed until ticket==512, acquire-fence once, then each computes one
// 128-row out tile. Deadlock-free (winners wait only on already-running
// blocks); ticket zeroed in prep (2 dispatches upstream, replay-safe).
// Saves one dispatch gap + out launch (~8-12us). (2) qkvz ez-section XCD
// swizzle: b = blk&7 so one batch's 64 tiles (sharing 256KB Hpb[b] panel)
// live on one XCD L2 (R33-proven mechanism). 3 dispatches total.

using u16 = unsigned short;
typedef short bf16x8 __attribute__((ext_vector_type(8)));
typedef float f32x4 __attribute__((ext_vector_type(4)));
typedef _Float16 f16;
typedef _Float16 f16x4 __attribute__((ext_vector_type(4)));

#define MFMA16(a, b, c) __builtin_amdgcn_mfma_f32_16x16x16f16(a, b, c, 0, 0, 0)
#define MFMAB(a, b, c) __builtin_amdgcn_mfma_f32_16x16x32_bf16(a, b, c, 0, 0, 0)

__device__ __forceinline__ u16 f2b(float f) {
    unsigned u = __float_as_uint(f);
    return (u16)((u + 0x7fffu + ((u >> 16) & 1u)) >> 16);  // RNE
}
__device__ __forceinline__ float b2f(u16 u) {
    return __uint_as_float(((unsigned)u) << 16);
}

// ---- merged prep + Hp-GEMM (R30 body + ticket zero) ----
__global__ void prep_hp(const float* __restrict__ H, const float* __restrict__ Wlin,
                        const float* __restrict__ Win,
                        const float* __restrict__ Wout, const float* __restrict__ Wfin,
                        const float* __restrict__ bout, const float* __restrict__ bfin,
                        const float* __restrict__ blin,
                        u16* __restrict__ WinTb, u16* __restrict__ WcombTb,
                        float* __restrict__ bcomb, float* __restrict__ rowsum,
                        u16* __restrict__ Hpb, unsigned* __restrict__ ticket) {
    if (blockIdx.x < 64) {
        const int m0 = blockIdx.x * 128;
        const int t = threadIdx.x;
        const int wave = t >> 6, lane = t & 63;
        const int wm = (wave >> 1) * 64, wn = (wave & 1) * 64;
        const int m16 = lane & 15, kq = lane >> 4;
        f32x4 acc[4][4] = {};

#pragma unroll
        for (int kc = 0; kc < 4; ++kc) {
            bf16x8 af[4], bf[4];
#pragma unroll
            for (int i = 0; i < 4; ++i) {
                const float* ap = &H[(long long)(m0 + wm + i * 16 + m16) * 128 + kc * 32 + kq * 8];
                float4 u0 = *(const float4*)ap;
                float4 u1 = *(const float4*)(ap + 4);
                bf16x8 a;
                a[0] = (short)f2b(u0.x); a[1] = (short)f2b(u0.y);
                a[2] = (short)f2b(u0.z); a[3] = (short)f2b(u0.w);
                a[4] = (short)f2b(u1.x); a[5] = (short)f2b(u1.y);
                a[6] = (short)f2b(u1.z); a[7] = (short)f2b(u1.w);
                af[i] = a;
            }
#pragma unroll
            for (int j = 0; j < 4; ++j) {
                const int col = wn + j * 16 + m16;
                const int k0 = kc * 32 + kq * 8;
                bf16x8 bb;
#pragma unroll
                for (int e = 0; e < 8; ++e)
                    bb[e] = (short)f2b(Wlin[(long long)(k0 + e) * 128 + col]);
                bf[j] = bb;
            }
#pragma unroll
            for (int i = 0; i < 4; ++i)
#pragma unroll
                for (int j = 0; j < 4; ++j)
                    acc[i][j] = MFMAB(af[i], bf[j], acc[i][j]);
        }
#pragma unroll
        for (int i = 0; i < 4; ++i) {
#pragma unroll
            for (int r = 0; r < 4; ++r) {
                long long row = m0 + wm + i * 16 + kq * 4 + r;
#pragma unroll
                for (int j = 0; j < 4; ++j) {
                    int col = wn + j * 16 + m16;
                    Hpb[row * 128 + col] = f2b(acc[i][j][r] + blin[col]);
                }
            }
        }
        return;
    }
    int i = (blockIdx.x - 64) * 256 + threadIdx.x;   // 0..81919
    if (i < 8192) rowsum[i] = 0.f;
    if (i == 8192) *ticket = 0;               // flash/out fusion counter
    if (i >= 16384 && i < 65536) {
        int k = i - 16384;                    // Win 128x384 -> WinTb 384x128 bf16
        int r = k / 384, c = k - r * 384;
        WinTb[c * 128 + r] = f2b(Win[k]);
    } else if (i >= 65536) {
        int k = i - 65536;
        int o = k & 127, e = k >> 7;          // o fastest: Wfin coalesced
        float s = 0.f;
        for (int kk = 0; kk < 128; ++kk)
            s = fmaf(Wout[e * 128 + kk], Wfin[kk * 128 + o], s);
        WcombTb[o * 128 + e] = f2b(s);
        if (e == 0) {
            float sb = bfin[o];
            for (int kk = 0; kk < 128; ++kk)
                sb = fmaf(bout[kk], Wfin[kk * 128 + o], sb);
            bcomb[o] = sb;
        }
    }
}

// ---- merged qkvz: ez section XCD-swizzled (b = blk&7) ----
__global__ __launch_bounds__(256)
void mfma_qkvz(const u16* __restrict__ Hpb, const u16* __restrict__ WinTb,
               const float* __restrict__ bin, f16* __restrict__ Cq,
               const float* __restrict__ Aadj, u16* __restrict__ EZ,
               float* __restrict__ rowsum) {
    const int blk = blockIdx.x;
    const int t = threadIdx.x;
    const int wave = t >> 6, lane = t & 63;
    const int wm = (wave >> 1) * 64, wn = (wave & 1) * 64;
    const int m16 = lane & 15, kq = lane >> 4;
    f32x4 acc[4][4] = {};

    if (blk < 512) {
        // XCD swizzle: batch = blk&7 -> all 64 tiles of one batch share one
        // XCD's L2 (256KB Hpb[b] panel fetched once).
        const int b = blk & 7, tile = blk >> 3;
        const int mt = tile >> 3, nt = tile & 7;
        const u16* Ab = Hpb + (long long)b * 1024 * 128;
        const int m0 = mt * 128, n0 = nt * 128;
#pragma unroll
        for (int kc = 0; kc < 4; ++kc) {
            bf16x8 af[4], bf[4];
#pragma unroll
            for (int i = 0; i < 4; ++i)
                af[i] = *(const bf16x8*)&Ab[(long long)(m0 + wm + i * 16 + m16) * 128 + kc * 32 + kq * 8];
#pragma unroll
            for (int j = 0; j < 4; ++j)
                bf[j] = *(const bf16x8*)&Ab[(long long)(n0 + wn + j * 16 + m16) * 128 + kc * 32 + kq * 8];
#pragma unroll
            for (int i = 0; i < 4; ++i)
#pragma unroll
                for (int j = 0; j < 4; ++j)
                    acc[i][j] = MFMAB(af[i], bf[j], acc[i][j]);
        }
        const long long zb = (long long)b * 1024 * 1024;
#pragma unroll
        for (int i = 0; i < 4; ++i) {
#pragma unroll
            for (int r = 0; r < 4; ++r) {
                int row = m0 + wm + i * 16 + kq * 4 + r;
                float es = 0.f;
#pragma unroll
                for (int j = 0; j < 4; ++j) {
                    int col = n0 + wn + j * 16 + m16;
                    float v = acc[i][j][r];
                    v = v >= 0.f ? v : 0.2f * v;                    // LeakyReLU(0.2)
                    if (Aadj[zb + (long long)row * 1024 + col] == 0.f) v = 0.f;  // gate
                    float ev = __expf(v);                           // m=0: |z| bounded
                    EZ[zb + (long long)row * 1024 + col] = f2b(ev);
                    es += ev;
                }
#pragma unroll
                for (int off = 1; off < 16; off <<= 1) es += __shfl_xor(es, off);
                if (m16 == 0) atomicAdd(&rowsum[b * 1024 + row], es);
            }
        }
    } else {
        const int q = blk - 512;
        const int mt = q & 63, slab = q >> 6;   // 0=q, 1=k, 2=v
        const int m0 = mt * 128;
        const u16* Bslab = WinTb + (long long)slab * 128 * 128;
#pragma unroll
        for (int kc = 0; kc < 4; ++kc) {
            bf16x8 af[4], bf[4];
#pragma unroll
            for (int i = 0; i < 4; ++i)
                af[i] = *(const bf16x8*)&Hpb[(long long)(m0 + wm + i * 16 + m16) * 128 + kc * 32 + kq * 8];
#pragma unroll
            for (int j = 0; j < 4; ++j)
                bf[j] = *(const bf16x8*)&Bslab[(long long)(wn + j * 16 + m16) * 128 + kc * 32 + kq * 8];
#pragma unroll
            for (int i = 0; i < 4; ++i)
#pragma unroll
                for (int j = 0; j < 4; ++j)
                    acc[i][j] = MFMAB(af[i], bf[j], acc[i][j]);
        }
        const float qscale = (slab == 0) ? 0.25f : 1.f;   // fold 1/sqrt(HD) into q
#pragma unroll
        for (int i = 0; i < 4; ++i) {
#pragma unroll
            for (int r = 0; r < 4; ++r) {
                long long row = m0 + wm + i * 16 + kq * 4 + r;
#pragma unroll
                for (int j = 0; j < 4; ++j) {
                    int col = wn + j * 16 + m16;
                    float v = (acc[i][j][r] + bin[slab * 128 + col]) * qscale;
                    Cq[row * 384 + slab * 128 + col] = (f16)v;
                }
            }
        }
    }
}

// ---- flash (R33 body: v1 + XCD swizzle) + fused out epilogue ----
__global__ __launch_bounds__(256)
void flash_mfma(const f16* __restrict__ qkv, const u16* __restrict__ ez,
                const float* __restrict__ rowsum, u16* __restrict__ ob,
                const u16* __restrict__ WcombTb, const float* __restrict__ bcomb,
                float* __restrict__ out, unsigned* __restrict__ ticket) {
    const int bid = blockIdx.x;
    const int xcd = bid & 7;
    const int rr_ = bid >> 3;
    const int hpair = rr_ & 3;
    const int g = rr_ >> 2;
    const int pair = g * 8 + xcd;        // 0..127 = (b, qblk)
    const int n0 = (pair & 15) * 64;     // qblk
    const int b = pair >> 4;             // batch
    const int h0 = hpair * 2;            // 2 heads per block
    const int t = threadIdx.x;
    const int w = t >> 6, lane = t & 63;
    const int qr16 = lane & 15, quad = lane >> 4;

    __shared__ u16 Ks[64 * 40];    // [key][dim 0..31 of head pair], stride 40
    __shared__ u16 VTs[32 * 76];   // [dim 0..31][key], stride 76 (bank-safe)
    __shared__ u16 AWs[64 * 72];   // [qrow 0..63][key 0..63] bf16 (ez)
    __shared__ unsigned tk_s;

    const int qrow_l = w * 16 + qr16;                 // block-local qrow
    const long long qrow_g = b * 1024 + n0 + qrow_l;  // global qrow
    const float inv0 = 1.f / rowsum[qrow_g];

    f16x4 qf[2];
#pragma unroll
    for (int hh = 0; hh < 2; ++hh)
        qf[hh] = *(const f16x4*)&qkv[qrow_g * 384 + (h0 + hh) * 16 + quad * 4];

    f32x4 accO[2] = {};
    float lacc[2] = {0.f, 0.f};

    for (int st = 0; st < 16; ++st) {
        const int kb = st * 64;
        __syncthreads();
        // stage K (64 keys x 32 dims) b128: key = t>>2, c8 = t&3
        {
            const int key = t >> 2, c8 = t & 3;
            *(uint4*)&Ks[key * 40 + c8 * 8] =
                *(const uint4*)&qkv[((long long)(b * 1024 + kb + key)) * 384 + 128 + h0 * 16 + c8 * 8];
            // stage V transposed: VTs[dim][key]; write bank-step 16 -> <=2-way
            const f16* vsrc = &qkv[((long long)(b * 1024 + kb + key)) * 384 + 256 + h0 * 16 + c8 * 8];
            f16x4 v0 = *(const f16x4*)vsrc;
            f16x4 v1 = *(const f16x4*)(vsrc + 4);
            const int d0 = c8 * 8;
#pragma unroll
            for (int i = 0; i < 4; ++i) {
                VTs[(d0 + i) * 76 + key] = ((const u16*)&v0)[i];
                VTs[(d0 + 4 + i) * 76 + key] = ((const u16*)&v1)[i];
            }
        }
        // stage AW (64 qrows x 64 keys) b128
#pragma unroll
        for (int rr = 0; rr < 2; ++rr) {
            int idx = rr * 256 + t;
            int row = idx >> 3, c16 = idx & 7;
            *(uint4*)&AWs[row * 72 + c16 * 8] =
                *(const uint4*)&ez[((long long)(b * 1024 + n0 + row)) * 1024 + kb + c16 * 8];
        }
        __syncthreads();

#pragma unroll 2
        for (int kt = 0; kt < 4; ++kt) {
            // aw C-init: lane holds (qrow=qr16, keys kt*16+quad*4+r)
            ushort4 ue = *(const ushort4*)&AWs[qrow_l * 72 + kt * 16 + quad * 4];
            f32x4 aw0;
            aw0[0] = b2f(ue.x) * inv0; aw0[1] = b2f(ue.y) * inv0;
            aw0[2] = b2f(ue.z) * inv0; aw0[3] = b2f(ue.w) * inv0;
#pragma unroll
            for (int hh = 0; hh < 2; ++hh) {
                f16x4 kf = *(const f16x4*)&Ks[(kt * 16 + qr16) * 40 + hh * 16 + quad * 4];
                f32x4 s4 = MFMA16(kf, qf[hh], aw0);
                float p0 = __expf(s4[0]), p1 = __expf(s4[1]);
                float p2 = __expf(s4[2]), p3 = __expf(s4[3]);
                lacc[hh] += (p0 + p1) + (p2 + p3);
                f16x4 pf;
                pf[0] = (f16)p0; pf[1] = (f16)p1; pf[2] = (f16)p2; pf[3] = (f16)p3;
                f16x4 vf = *(const f16x4*)&VTs[(hh * 16 + qr16) * 76 + kt * 16 + quad * 4];
                accO[hh] = MFMA16(vf, pf, accO[hh]);
            }
        }
    }
    // finalize: l over quads, store o normalized as bf16
#pragma unroll
    for (int hh = 0; hh < 2; ++hh) {
        float l = lacc[hh];
        l += __shfl_xor(l, 16);
        l += __shfl_xor(l, 32);
        float inv = 1.f / l;
        ushort4 st4;
        st4.x = f2b(accO[hh][0] * inv);
        st4.y = f2b(accO[hh][1] * inv);
        st4.z = f2b(accO[hh][2] * inv);
        st4.w = f2b(accO[hh][3] * inv);
        *(ushort4*)&ob[qrow_g * 128 + (h0 + hh) * 16 + quad * 4] = st4;
    }

    // ---- fused out epilogue: last 64 arrivals each do one 128-row tile ----
    __syncthreads();                      // all ob stores vmcnt-drained
    if (t == 0) {
        __threadfence();                  // release: writeback ob to device
        tk_s = __hip_atomic_fetch_add(ticket, 1u, __ATOMIC_RELAXED,
                                      __HIP_MEMORY_SCOPE_AGENT);
    }
    __syncthreads();
    const unsigned tk = tk_s;
    if (tk < 448u) return;                // early finishers exit
    if (t == 0) {
        while (__hip_atomic_load(ticket, __ATOMIC_RELAXED,
                                 __HIP_MEMORY_SCOPE_AGENT) < 512u)
            __builtin_amdgcn_s_sleep(8);
        __threadfence();                  // acquire: invalidate, see all ob
    }
    __syncthreads();
    {
        const int m0 = (int)(tk - 448u) * 128;
        const int wave = t >> 6;
        const int wm = (wave >> 1) * 64, wn = (wave & 1) * 64;
        const int m16 = lane & 15, kq = lane >> 4;
        f32x4 acc[4][4] = {};
#pragma unroll
        for (int kc = 0; kc < 4; ++kc) {
            bf16x8 af[4], bf[4];
#pragma unroll
            for (int i = 0; i < 4; ++i)
                af[i] = *(const bf16x8*)&ob[(long long)(m0 + wm + i * 16 + m16) * 128 + kc * 32 + kq * 8];
#pragma unroll
            for (int j = 0; j < 4; ++j)
                bf[j] = *(const bf16x8*)&WcombTb[(long long)(wn + j * 16 + m16) * 128 + kc * 32 + kq * 8];
#pragma unroll
            for (int i = 0; i < 4; ++i)
#pragma unroll
                for (int j = 0; j < 4; ++j)
                    acc[i][j] = MFMAB(af[i], bf[j], acc[i][j]);
        }
#pragma unroll
        for (int i = 0; i < 4; ++i) {
#pragma unroll
            for (int r = 0; r < 4; ++r) {
                long long row = m0 + wm + i * 16 + kq * 4 + r;
#pragma unroll
                for (int j = 0; j < 4; ++j) {
                    int col = wn + j * 16 + m16;
                    out[row * 128 + col] = acc[i][j][r] + bcomb[col];
                }
            }
        }
    }
}

extern "C" void kernel_launch(void* const* d_in, const int* in_sizes, int n_in,
                              void* d_out, int out_size, void* d_ws, size_t ws_size,
                              hipStream_t stream) {
    (void)in_sizes; (void)n_in; (void)out_size; (void)ws_size;
    const float* H    = (const float*)d_in[0];
    const float* Aadj = (const float*)d_in[1];
    const float* Wlin = (const float*)d_in[2];
    const float* blin = (const float*)d_in[3];
    const float* Win  = (const float*)d_in[4];
    const float* bin  = (const float*)d_in[5];
    const float* Wout = (const float*)d_in[6];
    const float* bout = (const float*)d_in[7];
    const float* Wfin = (const float*)d_in[8];
    const float* bfin = (const float*)d_in[9];
    float* out = (float*)d_out;
    char* ws = (char*)d_ws;

    u16*   WinTb   = (u16*)(ws + 0);          // 96 KB bf16
    u16*   WcombTb = (u16*)(ws + 98304);      // 32 KB bf16
    float* bcomb   = (float*)(ws + 131072);   // 512 B
    float* rowsum  = (float*)(ws + 131584);   // 32 KB
    u16*   Hpb     = (u16*)(ws + 262144);     // 2 MB bf16
    f16*   qkv     = (f16*)(ws + 2359296);    // 6 MB (q f16*0.25 | k f16 | v f16)
    u16*   ob      = (u16*)(ws + 8650752);    // 2 MB bf16 normalized o
    u16*   ez      = (u16*)(ws + 12845056);   // 16 MB bf16 exp(z)
    unsigned* ticket = (unsigned*)(ws + 29622272);  // flash->out fusion counter
    // total ~29 MB

    // prep: Hp MFMA (64 blocks) + weight transposes/combine + ticket zero
    prep_hp<<<384, 256, 0, stream>>>(H, Wlin, Win, Wout, Wfin, bout, bfin,
                                     blin, WinTb, WcombTb, bcomb, rowsum, Hpb,
                                     ticket);
    // merged: ez-gate (512 blocks, XCD-swizzled by batch) + qkv f16 (192)
    mfma_qkvz<<<704, 256, 0, stream>>>(Hpb, WinTb, bin, qkv, Aadj, ez, rowsum);
    // flash (XCD-swizzled) + fused out epilogue (ticket-gated last 64 blocks)
    flash_mfma<<<512, 256, 0, stream>>>(qkv, ez, rowsum, ob, WcombTb, bcomb,
                                        out, ticket);
}

// Round 10
// 158.755 us; speedup vs baseline: 1.1261x; 1.1261x over previous
//
#include <hip/hip_runtime.h>
#include <hip/hip_bf16.h>

// GraphAttentionLayer: B=8,N=1024,FIN=E=OUT=128,NH=8,HD=16. f32 in/out.
// R35: R33 (157.58us) + qkvz ez-section XCD swizzle ONLY. R34's ticket
// fusion REVERTED: 512 per-block release threadfences cost flash +33us
// (28->60.8) vs ~8us dispatch-gap saved -- software inter-block sync is
// 4-15x a dispatch boundary on this chip (3rd confirmation: R27/R28/R34).
// R34 accounting isolated qkvz swizzle at ~-3.6us (consistent with R33's
// flash swizzle -2.2us): kept. 4 dispatches; prep/flash/out = R33 bodies.

using u16 = unsigned short;
typedef short bf16x8 __attribute__((ext_vector_type(8)));
typedef float f32x4 __attribute__((ext_vector_type(4)));
typedef _Float16 f16;
typedef _Float16 f16x4 __attribute__((ext_vector_type(4)));

#define MFMA16(a, b, c) __builtin_amdgcn_mfma_f32_16x16x16f16(a, b, c, 0, 0, 0)
#define MFMAB(a, b, c) __builtin_amdgcn_mfma_f32_16x16x32_bf16(a, b, c, 0, 0, 0)

__device__ __forceinline__ u16 f2b(float f) {
    unsigned u = __float_as_uint(f);
    return (u16)((u + 0x7fffu + ((u >> 16) & 1u)) >> 16);  // RNE
}
__device__ __forceinline__ float b2f(u16 u) {
    return __uint_as_float(((unsigned)u) << 16);
}

// ---- merged prep + Hp-GEMM (byte-identical to R30/R33) ----
__global__ void prep_hp(const float* __restrict__ H, const float* __restrict__ Wlin,
                        const float* __restrict__ Win,
                        const float* __restrict__ Wout, const float* __restrict__ Wfin,
                        const float* __restrict__ bout, const float* __restrict__ bfin,
                        const float* __restrict__ blin,
                        u16* __restrict__ WinTb, u16* __restrict__ WcombTb,
                        float* __restrict__ bcomb, float* __restrict__ rowsum,
                        u16* __restrict__ Hpb) {
    if (blockIdx.x < 64) {
        const int m0 = blockIdx.x * 128;
        const int t = threadIdx.x;
        const int wave = t >> 6, lane = t & 63;
        const int wm = (wave >> 1) * 64, wn = (wave & 1) * 64;
        const int m16 = lane & 15, kq = lane >> 4;
        f32x4 acc[4][4] = {};

#pragma unroll
        for (int kc = 0; kc < 4; ++kc) {
            bf16x8 af[4], bf[4];
#pragma unroll
            for (int i = 0; i < 4; ++i) {
                const float* ap = &H[(long long)(m0 + wm + i * 16 + m16) * 128 + kc * 32 + kq * 8];
                float4 u0 = *(const float4*)ap;
                float4 u1 = *(const float4*)(ap + 4);
                bf16x8 a;
                a[0] = (short)f2b(u0.x); a[1] = (short)f2b(u0.y);
                a[2] = (short)f2b(u0.z); a[3] = (short)f2b(u0.w);
                a[4] = (short)f2b(u1.x); a[5] = (short)f2b(u1.y);
                a[6] = (short)f2b(u1.z); a[7] = (short)f2b(u1.w);
                af[i] = a;
            }
#pragma unroll
            for (int j = 0; j < 4; ++j) {
                const int col = wn + j * 16 + m16;
                const int k0 = kc * 32 + kq * 8;
                bf16x8 bb;
#pragma unroll
                for (int e = 0; e < 8; ++e)
                    bb[e] = (short)f2b(Wlin[(long long)(k0 + e) * 128 + col]);
                bf[j] = bb;
            }
#pragma unroll
            for (int i = 0; i < 4; ++i)
#pragma unroll
                for (int j = 0; j < 4; ++j)
                    acc[i][j] = MFMAB(af[i], bf[j], acc[i][j]);
        }
#pragma unroll
        for (int i = 0; i < 4; ++i) {
#pragma unroll
            for (int r = 0; r < 4; ++r) {
                long long row = m0 + wm + i * 16 + kq * 4 + r;
#pragma unroll
                for (int j = 0; j < 4; ++j) {
                    int col = wn + j * 16 + m16;
                    Hpb[row * 128 + col] = f2b(acc[i][j][r] + blin[col]);
                }
            }
        }
        return;
    }
    int i = (blockIdx.x - 64) * 256 + threadIdx.x;   // 0..81919
    if (i < 8192) rowsum[i] = 0.f;
    if (i >= 16384 && i < 65536) {
        int k = i - 16384;                    // Win 128x384 -> WinTb 384x128 bf16
        int r = k / 384, c = k - r * 384;
        WinTb[c * 128 + r] = f2b(Win[k]);
    } else if (i >= 65536) {
        int k = i - 65536;
        int o = k & 127, e = k >> 7;          // o fastest: Wfin coalesced
        float s = 0.f;
        for (int kk = 0; kk < 128; ++kk)
            s = fmaf(Wout[e * 128 + kk], Wfin[kk * 128 + o], s);
        WcombTb[o * 128 + e] = f2b(s);
        if (e == 0) {
            float sb = bfin[o];
            for (int kk = 0; kk < 128; ++kk)
                sb = fmaf(bout[kk], Wfin[kk * 128 + o], sb);
            bcomb[o] = sb;
        }
    }
}

// ---- merged qkvz: ez section XCD-swizzled (b = blk&7, R34-isolated -3.6us) ----
__global__ __launch_bounds__(256)
void mfma_qkvz(const u16* __restrict__ Hpb, const u16* __restrict__ WinTb,
               const float* __restrict__ bin, f16* __restrict__ Cq,
               const float* __restrict__ Aadj, u16* __restrict__ EZ,
               float* __restrict__ rowsum) {
    const int blk = blockIdx.x;
    const int t = threadIdx.x;
    const int wave = t >> 6, lane = t & 63;
    const int wm = (wave >> 1) * 64, wn = (wave & 1) * 64;
    const int m16 = lane & 15, kq = lane >> 4;
    f32x4 acc[4][4] = {};

    if (blk < 512) {
        // XCD swizzle: batch = blk&7 -> all 64 tiles of one batch share one
        // XCD's L2 (256KB Hpb[b] panel fetched once).
        const int b = blk & 7, tile = blk >> 3;
        const int mt = tile >> 3, nt = tile & 7;
        const u16* Ab = Hpb + (long long)b * 1024 * 128;
        const int m0 = mt * 128, n0 = nt * 128;
#pragma unroll
        for (int kc = 0; kc < 4; ++kc) {
            bf16x8 af[4], bf[4];
#pragma unroll
            for (int i = 0; i < 4; ++i)
                af[i] = *(const bf16x8*)&Ab[(long long)(m0 + wm + i * 16 + m16) * 128 + kc * 32 + kq * 8];
#pragma unroll
            for (int j = 0; j < 4; ++j)
                bf[j] = *(const bf16x8*)&Ab[(long long)(n0 + wn + j * 16 + m16) * 128 + kc * 32 + kq * 8];
#pragma unroll
            for (int i = 0; i < 4; ++i)
#pragma unroll
                for (int j = 0; j < 4; ++j)
                    acc[i][j] = MFMAB(af[i], bf[j], acc[i][j]);
        }
        const long long zb = (long long)b * 1024 * 1024;
#pragma unroll
        for (int i = 0; i < 4; ++i) {
#pragma unroll
            for (int r = 0; r < 4; ++r) {
                int row = m0 + wm + i * 16 + kq * 4 + r;
                float es = 0.f;
#pragma unroll
                for (int j = 0; j < 4; ++j) {
                    int col = n0 + wn + j * 16 + m16;
                    float v = acc[i][j][r];
                    v = v >= 0.f ? v : 0.2f * v;                    // LeakyReLU(0.2)
                    if (Aadj[zb + (long long)row * 1024 + col] == 0.f) v = 0.f;  // gate
                    float ev = __expf(v);                           // m=0: |z| bounded
                    EZ[zb + (long long)row * 1024 + col] = f2b(ev);
                    es += ev;
                }
#pragma unroll
                for (int off = 1; off < 16; off <<= 1) es += __shfl_xor(es, off);
                if (m16 == 0) atomicAdd(&rowsum[b * 1024 + row], es);
            }
        }
    } else {
        const int q = blk - 512;
        const int mt = q & 63, slab = q >> 6;   // 0=q, 1=k, 2=v
        const int m0 = mt * 128;
        const u16* Bslab = WinTb + (long long)slab * 128 * 128;
#pragma unroll
        for (int kc = 0; kc < 4; ++kc) {
            bf16x8 af[4], bf[4];
#pragma unroll
            for (int i = 0; i < 4; ++i)
                af[i] = *(const bf16x8*)&Hpb[(long long)(m0 + wm + i * 16 + m16) * 128 + kc * 32 + kq * 8];
#pragma unroll
            for (int j = 0; j < 4; ++j)
                bf[j] = *(const bf16x8*)&Bslab[(long long)(wn + j * 16 + m16) * 128 + kc * 32 + kq * 8];
#pragma unroll
            for (int i = 0; i < 4; ++i)
#pragma unroll
                for (int j = 0; j < 4; ++j)
                    acc[i][j] = MFMAB(af[i], bf[j], acc[i][j]);
        }
        const float qscale = (slab == 0) ? 0.25f : 1.f;   // fold 1/sqrt(HD) into q
#pragma unroll
        for (int i = 0; i < 4; ++i) {
#pragma unroll
            for (int r = 0; r < 4; ++r) {
                long long row = m0 + wm + i * 16 + kq * 4 + r;
#pragma unroll
                for (int j = 0; j < 4; ++j) {
                    int col = wn + j * 16 + m16;
                    float v = (acc[i][j][r] + bin[slab * 128 + col]) * qscale;
                    Cq[row * 384 + slab * 128 + col] = (f16)v;
                }
            }
        }
    }
}

// ---- flash (byte-identical to R33: v1 body + XCD swizzle) ----
__global__ __launch_bounds__(256)
void flash_mfma(const f16* __restrict__ qkv, const u16* __restrict__ ez,
                const float* __restrict__ rowsum, u16* __restrict__ ob) {
    const int bid = blockIdx.x;
    const int xcd = bid & 7;
    const int rr_ = bid >> 3;
    const int hpair = rr_ & 3;
    const int g = rr_ >> 2;
    const int pair = g * 8 + xcd;        // 0..127 = (b, qblk)
    const int n0 = (pair & 15) * 64;     // qblk
    const int b = pair >> 4;             // batch
    const int h0 = hpair * 2;            // 2 heads per block
    const int t = threadIdx.x;
    const int w = t >> 6, lane = t & 63;
    const int qr16 = lane & 15, quad = lane >> 4;

    __shared__ u16 Ks[64 * 40];    // [key][dim 0..31 of head pair], stride 40
    __shared__ u16 VTs[32 * 76];   // [dim 0..31][key], stride 76 (bank-safe)
    __shared__ u16 AWs[64 * 72];   // [qrow 0..63][key 0..63] bf16 (ez)

    const int qrow_l = w * 16 + qr16;                 // block-local qrow
    const long long qrow_g = b * 1024 + n0 + qrow_l;  // global qrow
    const float inv0 = 1.f / rowsum[qrow_g];

    f16x4 qf[2];
#pragma unroll
    for (int hh = 0; hh < 2; ++hh)
        qf[hh] = *(const f16x4*)&qkv[qrow_g * 384 + (h0 + hh) * 16 + quad * 4];

    f32x4 accO[2] = {};
    float lacc[2] = {0.f, 0.f};

    for (int st = 0; st < 16; ++st) {
        const int kb = st * 64;
        __syncthreads();
        // stage K (64 keys x 32 dims) b128: key = t>>2, c8 = t&3
        {
            const int key = t >> 2, c8 = t & 3;
            *(uint4*)&Ks[key * 40 + c8 * 8] =
                *(const uint4*)&qkv[((long long)(b * 1024 + kb + key)) * 384 + 128 + h0 * 16 + c8 * 8];
            // stage V transposed: VTs[dim][key]; write bank-step 16 -> <=2-way
            const f16* vsrc = &qkv[((long long)(b * 1024 + kb + key)) * 384 + 256 + h0 * 16 + c8 * 8];
            f16x4 v0 = *(const f16x4*)vsrc;
            f16x4 v1 = *(const f16x4*)(vsrc + 4);
            const int d0 = c8 * 8;
#pragma unroll
            for (int i = 0; i < 4; ++i) {
                VTs[(d0 + i) * 76 + key] = ((const u16*)&v0)[i];
                VTs[(d0 + 4 + i) * 76 + key] = ((const u16*)&v1)[i];
            }
        }
        // stage AW (64 qrows x 64 keys) b128
#pragma unroll
        for (int rr = 0; rr < 2; ++rr) {
            int idx = rr * 256 + t;
            int row = idx >> 3, c16 = idx & 7;
            *(uint4*)&AWs[row * 72 + c16 * 8] =
                *(const uint4*)&ez[((long long)(b * 1024 + n0 + row)) * 1024 + kb + c16 * 8];
        }
        __syncthreads();

#pragma unroll 2
        for (int kt = 0; kt < 4; ++kt) {
            // aw C-init: lane holds (qrow=qr16, keys kt*16+quad*4+r)
            ushort4 ue = *(const ushort4*)&AWs[qrow_l * 72 + kt * 16 + quad * 4];
            f32x4 aw0;
            aw0[0] = b2f(ue.x) * inv0; aw0[1] = b2f(ue.y) * inv0;
            aw0[2] = b2f(ue.z) * inv0; aw0[3] = b2f(ue.w) * inv0;
#pragma unroll
            for (int hh = 0; hh < 2; ++hh) {
                f16x4 kf = *(const f16x4*)&Ks[(kt * 16 + qr16) * 40 + hh * 16 + quad * 4];
                f32x4 s4 = MFMA16(kf, qf[hh], aw0);
                float p0 = __expf(s4[0]), p1 = __expf(s4[1]);
                float p2 = __expf(s4[2]), p3 = __expf(s4[3]);
                lacc[hh] += (p0 + p1) + (p2 + p3);
                f16x4 pf;
                pf[0] = (f16)p0; pf[1] = (f16)p1; pf[2] = (f16)p2; pf[3] = (f16)p3;
                f16x4 vf = *(const f16x4*)&VTs[(hh * 16 + qr16) * 76 + kt * 16 + quad * 4];
                accO[hh] = MFMA16(vf, pf, accO[hh]);
            }
        }
    }
    // finalize: l over quads, store o normalized as bf16
#pragma unroll
    for (int hh = 0; hh < 2; ++hh) {
        float l = lacc[hh];
        l += __shfl_xor(l, 16);
        l += __shfl_xor(l, 32);
        float inv = 1.f / l;
        ushort4 st4;
        st4.x = f2b(accO[hh][0] * inv);
        st4.y = f2b(accO[hh][1] * inv);
        st4.z = f2b(accO[hh][2] * inv);
        st4.w = f2b(accO[hh][3] * inv);
        *(ushort4*)&ob[qrow_g * 128 + (h0 + hh) * 16 + quad * 4] = st4;
    }
}

// -------- out = ob @ WcombTb^T + bcomb (byte-identical to R30/R33) --------
__global__ __launch_bounds__(256)
void mfma_out(const u16* __restrict__ A, const u16* __restrict__ Bb,
              const float* __restrict__ bias, float* __restrict__ C) {
    const int m0 = blockIdx.x * 128;
    const int t = threadIdx.x;
    const int wave = t >> 6, lane = t & 63;
    const int wm = (wave >> 1) * 64, wn = (wave & 1) * 64;
    const int m16 = lane & 15, kq = lane >> 4;
    f32x4 acc[4][4] = {};

#pragma unroll
    for (int kc = 0; kc < 4; ++kc) {
        bf16x8 af[4], bf[4];
#pragma unroll
        for (int i = 0; i < 4; ++i)
            af[i] = *(const bf16x8*)&A[(long long)(m0 + wm + i * 16 + m16) * 128 + kc * 32 + kq * 8];
#pragma unroll
        for (int j = 0; j < 4; ++j)
            bf[j] = *(const bf16x8*)&Bb[(long long)(wn + j * 16 + m16) * 128 + kc * 32 + kq * 8];
#pragma unroll
        for (int i = 0; i < 4; ++i)
#pragma unroll
            for (int j = 0; j < 4; ++j)
                acc[i][j] = MFMAB(af[i], bf[j], acc[i][j]);
    }
#pragma unroll
    for (int i = 0; i < 4; ++i) {
#pragma unroll
        for (int r = 0; r < 4; ++r) {
            long long row = m0 + wm + i * 16 + kq * 4 + r;
#pragma unroll
            for (int j = 0; j < 4; ++j) {
                int col = wn + j * 16 + m16;
                C[row * 128 + col] = acc[i][j][r] + bias[col];
            }
        }
    }
}

extern "C" void kernel_launch(void* const* d_in, const int* in_sizes, int n_in,
                              void* d_out, int out_size, void* d_ws, size_t ws_size,
                              hipStream_t stream) {
    (void)in_sizes; (void)n_in; (void)out_size; (void)ws_size;
    const float* H    = (const float*)d_in[0];
    const float* Aadj = (const float*)d_in[1];
    const float* Wlin = (const float*)d_in[2];
    const float* blin = (const float*)d_in[3];
    const float* Win  = (const float*)d_in[4];
    const float* bin  = (const float*)d_in[5];
    const float* Wout = (const float*)d_in[6];
    const float* bout = (const float*)d_in[7];
    const float* Wfin = (const float*)d_in[8];
    const float* bfin = (const float*)d_in[9];
    float* out = (float*)d_out;
    char* ws = (char*)d_ws;

    u16*   WinTb   = (u16*)(ws + 0);          // 96 KB bf16
    u16*   WcombTb = (u16*)(ws + 98304);      // 32 KB bf16
    float* bcomb   = (float*)(ws + 131072);   // 512 B
    float* rowsum  = (float*)(ws + 131584);   // 32 KB
    u16*   Hpb     = (u16*)(ws + 262144);     // 2 MB bf16
    f16*   qkv     = (f16*)(ws + 2359296);    // 6 MB (q f16*0.25 | k f16 | v f16)
    u16*   ob      = (u16*)(ws + 8650752);    // 2 MB bf16 normalized o
    u16*   ez      = (u16*)(ws + 12845056);   // 16 MB bf16 exp(z)
    // total ~29 MB

    // prep: Hp MFMA (64 blocks) + weight transposes/combine (320 blocks)
    prep_hp<<<384, 256, 0, stream>>>(H, Wlin, Win, Wout, Wfin, bout, bfin,
                                     blin, WinTb, WcombTb, bcomb, rowsum, Hpb);
    // merged: ez-gate (512 blocks, XCD-swizzled by batch) + qkv f16 (192)
    mfma_qkvz<<<704, 256, 0, stream>>>(Hpb, WinTb, bin, qkv, Aadj, ez, rowsum);
    // flash (XCD-swizzled, v1 body)
    flash_mfma<<<512, 256, 0, stream>>>(qkv, ez, rowsum, ob);
    // out = ob @ WcombTb^T + bcomb  (MFMA)
    mfma_out<<<64, 256, 0, stream>>>(ob, WcombTb, bcomb, out);
}

// Round 11
// 155.402 us; speedup vs baseline: 1.1504x; 1.0216x over previous
//
#include <hip/hip_runtime.h>
#include <hip/hip_bf16.h>

// GraphAttentionLayer: B=8,N=1024,FIN=E=OUT=128,NH=8,HD=16. f32 in/out.
// R36: vs R35 (158.75us; R33 157.58 == tie within +-1.5us noise): flash
// split to ONE HEAD PER BLOCK -> grid 1024 = 4 blk/CU (was 512 = 2/CU;
// occupancy was grid-capped, not resource-capped: 19KB LDS / 76 VGPR allow
// 6+). Flash is latency-bound (R32/R34: MfmaUtil 5%, Occ 14%) -- 2x
// co-residency doubles barrier-window overlap. Per-head math untouched
// (qf/accO/lacc were already per-head independent) -> output bit-identical,
// absmax must stay exactly 9.155273e-05. LDS 14.7KB/block (Ks 64x24 16-dim,
// VTs 16x76, AWs 64x72). AW staging duplicated across head-siblings: +16MB
// L2-resident ez reads (~1us L2 BW), XCD swizzle keeps all 8 heads of one
// (b,qblk) on one XCD. prep/qkvz/out byte-identical to R35.

using u16 = unsigned short;
typedef short bf16x8 __attribute__((ext_vector_type(8)));
typedef float f32x4 __attribute__((ext_vector_type(4)));
typedef _Float16 f16;
typedef _Float16 f16x4 __attribute__((ext_vector_type(4)));

#define MFMA16(a, b, c) __builtin_amdgcn_mfma_f32_16x16x16f16(a, b, c, 0, 0, 0)
#define MFMAB(a, b, c) __builtin_amdgcn_mfma_f32_16x16x32_bf16(a, b, c, 0, 0, 0)

__device__ __forceinline__ u16 f2b(float f) {
    unsigned u = __float_as_uint(f);
    return (u16)((u + 0x7fffu + ((u >> 16) & 1u)) >> 16);  // RNE
}
__device__ __forceinline__ float b2f(u16 u) {
    return __uint_as_float(((unsigned)u) << 16);
}

// ---- merged prep + Hp-GEMM (byte-identical to R30/R33/R35) ----
__global__ void prep_hp(const float* __restrict__ H, const float* __restrict__ Wlin,
                        const float* __restrict__ Win,
                        const float* __restrict__ Wout, const float* __restrict__ Wfin,
                        const float* __restrict__ bout, const float* __restrict__ bfin,
                        const float* __restrict__ blin,
                        u16* __restrict__ WinTb, u16* __restrict__ WcombTb,
                        float* __restrict__ bcomb, float* __restrict__ rowsum,
                        u16* __restrict__ Hpb) {
    if (blockIdx.x < 64) {
        const int m0 = blockIdx.x * 128;
        const int t = threadIdx.x;
        const int wave = t >> 6, lane = t & 63;
        const int wm = (wave >> 1) * 64, wn = (wave & 1) * 64;
        const int m16 = lane & 15, kq = lane >> 4;
        f32x4 acc[4][4] = {};

#pragma unroll
        for (int kc = 0; kc < 4; ++kc) {
            bf16x8 af[4], bf[4];
#pragma unroll
            for (int i = 0; i < 4; ++i) {
                const float* ap = &H[(long long)(m0 + wm + i * 16 + m16) * 128 + kc * 32 + kq * 8];
                float4 u0 = *(const float4*)ap;
                float4 u1 = *(const float4*)(ap + 4);
                bf16x8 a;
                a[0] = (short)f2b(u0.x); a[1] = (short)f2b(u0.y);
                a[2] = (short)f2b(u0.z); a[3] = (short)f2b(u0.w);
                a[4] = (short)f2b(u1.x); a[5] = (short)f2b(u1.y);
                a[6] = (short)f2b(u1.z); a[7] = (short)f2b(u1.w);
                af[i] = a;
            }
#pragma unroll
            for (int j = 0; j < 4; ++j) {
                const int col = wn + j * 16 + m16;
                const int k0 = kc * 32 + kq * 8;
                bf16x8 bb;
#pragma unroll
                for (int e = 0; e < 8; ++e)
                    bb[e] = (short)f2b(Wlin[(long long)(k0 + e) * 128 + col]);
                bf[j] = bb;
            }
#pragma unroll
            for (int i = 0; i < 4; ++i)
#pragma unroll
                for (int j = 0; j < 4; ++j)
                    acc[i][j] = MFMAB(af[i], bf[j], acc[i][j]);
        }
#pragma unroll
        for (int i = 0; i < 4; ++i) {
#pragma unroll
            for (int r = 0; r < 4; ++r) {
                long long row = m0 + wm + i * 16 + kq * 4 + r;
#pragma unroll
                for (int j = 0; j < 4; ++j) {
                    int col = wn + j * 16 + m16;
                    Hpb[row * 128 + col] = f2b(acc[i][j][r] + blin[col]);
                }
            }
        }
        return;
    }
    int i = (blockIdx.x - 64) * 256 + threadIdx.x;   // 0..81919
    if (i < 8192) rowsum[i] = 0.f;
    if (i >= 16384 && i < 65536) {
        int k = i - 16384;                    // Win 128x384 -> WinTb 384x128 bf16
        int r = k / 384, c = k - r * 384;
        WinTb[c * 128 + r] = f2b(Win[k]);
    } else if (i >= 65536) {
        int k = i - 65536;
        int o = k & 127, e = k >> 7;          // o fastest: Wfin coalesced
        float s = 0.f;
        for (int kk = 0; kk < 128; ++kk)
            s = fmaf(Wout[e * 128 + kk], Wfin[kk * 128 + o], s);
        WcombTb[o * 128 + e] = f2b(s);
        if (e == 0) {
            float sb = bfin[o];
            for (int kk = 0; kk < 128; ++kk)
                sb = fmaf(bout[kk], Wfin[kk * 128 + o], sb);
            bcomb[o] = sb;
        }
    }
}

// ---- merged qkvz (byte-identical to R35) ----
__global__ __launch_bounds__(256)
void mfma_qkvz(const u16* __restrict__ Hpb, const u16* __restrict__ WinTb,
               const float* __restrict__ bin, f16* __restrict__ Cq,
               const float* __restrict__ Aadj, u16* __restrict__ EZ,
               float* __restrict__ rowsum) {
    const int blk = blockIdx.x;
    const int t = threadIdx.x;
    const int wave = t >> 6, lane = t & 63;
    const int wm = (wave >> 1) * 64, wn = (wave & 1) * 64;
    const int m16 = lane & 15, kq = lane >> 4;
    f32x4 acc[4][4] = {};

    if (blk < 512) {
        // XCD swizzle: batch = blk&7 -> one batch's tiles share one XCD L2.
        const int b = blk & 7, tile = blk >> 3;
        const int mt = tile >> 3, nt = tile & 7;
        const u16* Ab = Hpb + (long long)b * 1024 * 128;
        const int m0 = mt * 128, n0 = nt * 128;
#pragma unroll
        for (int kc = 0; kc < 4; ++kc) {
            bf16x8 af[4], bf[4];
#pragma unroll
            for (int i = 0; i < 4; ++i)
                af[i] = *(const bf16x8*)&Ab[(long long)(m0 + wm + i * 16 + m16) * 128 + kc * 32 + kq * 8];
#pragma unroll
            for (int j = 0; j < 4; ++j)
                bf[j] = *(const bf16x8*)&Ab[(long long)(n0 + wn + j * 16 + m16) * 128 + kc * 32 + kq * 8];
#pragma unroll
            for (int i = 0; i < 4; ++i)
#pragma unroll
                for (int j = 0; j < 4; ++j)
                    acc[i][j] = MFMAB(af[i], bf[j], acc[i][j]);
        }
        const long long zb = (long long)b * 1024 * 1024;
#pragma unroll
        for (int i = 0; i < 4; ++i) {
#pragma unroll
            for (int r = 0; r < 4; ++r) {
                int row = m0 + wm + i * 16 + kq * 4 + r;
                float es = 0.f;
#pragma unroll
                for (int j = 0; j < 4; ++j) {
                    int col = n0 + wn + j * 16 + m16;
                    float v = acc[i][j][r];
                    v = v >= 0.f ? v : 0.2f * v;                    // LeakyReLU(0.2)
                    if (Aadj[zb + (long long)row * 1024 + col] == 0.f) v = 0.f;  // gate
                    float ev = __expf(v);                           // m=0: |z| bounded
                    EZ[zb + (long long)row * 1024 + col] = f2b(ev);
                    es += ev;
                }
#pragma unroll
                for (int off = 1; off < 16; off <<= 1) es += __shfl_xor(es, off);
                if (m16 == 0) atomicAdd(&rowsum[b * 1024 + row], es);
            }
        }
    } else {
        const int q = blk - 512;
        const int mt = q & 63, slab = q >> 6;   // 0=q, 1=k, 2=v
        const int m0 = mt * 128;
        const u16* Bslab = WinTb + (long long)slab * 128 * 128;
#pragma unroll
        for (int kc = 0; kc < 4; ++kc) {
            bf16x8 af[4], bf[4];
#pragma unroll
            for (int i = 0; i < 4; ++i)
                af[i] = *(const bf16x8*)&Hpb[(long long)(m0 + wm + i * 16 + m16) * 128 + kc * 32 + kq * 8];
#pragma unroll
            for (int j = 0; j < 4; ++j)
                bf[j] = *(const bf16x8*)&Bslab[(long long)(wn + j * 16 + m16) * 128 + kc * 32 + kq * 8];
#pragma unroll
            for (int i = 0; i < 4; ++i)
#pragma unroll
                for (int j = 0; j < 4; ++j)
                    acc[i][j] = MFMAB(af[i], bf[j], acc[i][j]);
        }
        const float qscale = (slab == 0) ? 0.25f : 1.f;   // fold 1/sqrt(HD) into q
#pragma unroll
        for (int i = 0; i < 4; ++i) {
#pragma unroll
            for (int r = 0; r < 4; ++r) {
                long long row = m0 + wm + i * 16 + kq * 4 + r;
#pragma unroll
                for (int j = 0; j < 4; ++j) {
                    int col = wn + j * 16 + m16;
                    float v = (acc[i][j][r] + bin[slab * 128 + col]) * qscale;
                    Cq[row * 384 + slab * 128 + col] = (f16)v;
                }
            }
        }
    }
}

// ---- flash: ONE head per block, 1024 blocks = 4 blk/CU. Per-head math
// identical to R35 (hh loop split across blocks) -> bit-identical output.
// XCD swizzle: all 8 heads of one (b,qblk) on one XCD (shared ez slice). ----
__global__ __launch_bounds__(256)
void flash_mfma(const f16* __restrict__ qkv, const u16* __restrict__ ez,
                const float* __restrict__ rowsum, u16* __restrict__ ob) {
    const int bid = blockIdx.x;
    const int xcd = bid & 7;
    const int rr_ = bid >> 3;
    const int h = rr_ & 7;               // head 0..7
    const int g = rr_ >> 3;              // 0..15
    const int pair = g * 8 + xcd;        // 0..127 = (b, qblk)
    const int n0 = (pair & 15) * 64;     // qblk
    const int b = pair >> 4;             // batch
    const int t = threadIdx.x;
    const int w = t >> 6, lane = t & 63;
    const int qr16 = lane & 15, quad = lane >> 4;

    __shared__ u16 Ks[64 * 24];    // [key][dim 0..15 of head], stride 24
    __shared__ u16 VTs[16 * 76];   // [dim 0..15][key], stride 76 (bank-safe)
    __shared__ u16 AWs[64 * 72];   // [qrow 0..63][key 0..63] bf16 (ez)

    const int qrow_l = w * 16 + qr16;                 // block-local qrow
    const long long qrow_g = b * 1024 + n0 + qrow_l;  // global qrow
    const float inv0 = 1.f / rowsum[qrow_g];

    f16x4 qf = *(const f16x4*)&qkv[qrow_g * 384 + h * 16 + quad * 4];

    f32x4 accO = {};
    float lacc = 0.f;

    for (int st = 0; st < 16; ++st) {
        const int kb = st * 64;
        __syncthreads();
        // stage K (64 keys x 16 dims) uint2: key = t>>2, c4 = t&3
        {
            const int key = t >> 2, c4 = t & 3;
            const long long kr = ((long long)(b * 1024 + kb + key)) * 384;
            *(uint2*)&Ks[key * 24 + c4 * 4] =
                *(const uint2*)&qkv[kr + 128 + h * 16 + c4 * 4];
            // stage V transposed: VTs[dim][key]
            f16x4 v0;
            *(uint2*)&v0 = *(const uint2*)&qkv[kr + 256 + h * 16 + c4 * 4];
            const int d0 = c4 * 4;
#pragma unroll
            for (int i = 0; i < 4; ++i)
                VTs[(d0 + i) * 76 + key] = ((const u16*)&v0)[i];
        }
        // stage AW (64 qrows x 64 keys) b128
#pragma unroll
        for (int rr2 = 0; rr2 < 2; ++rr2) {
            int idx = rr2 * 256 + t;
            int row = idx >> 3, c16 = idx & 7;
            *(uint4*)&AWs[row * 72 + c16 * 8] =
                *(const uint4*)&ez[((long long)(b * 1024 + n0 + row)) * 1024 + kb + c16 * 8];
        }
        __syncthreads();

#pragma unroll 2
        for (int kt = 0; kt < 4; ++kt) {
            // aw C-init: lane holds (qrow=qr16, keys kt*16+quad*4+r)
            ushort4 ue = *(const ushort4*)&AWs[qrow_l * 72 + kt * 16 + quad * 4];
            f32x4 aw0;
            aw0[0] = b2f(ue.x) * inv0; aw0[1] = b2f(ue.y) * inv0;
            aw0[2] = b2f(ue.z) * inv0; aw0[3] = b2f(ue.w) * inv0;
            f16x4 kf = *(const f16x4*)&Ks[(kt * 16 + qr16) * 24 + quad * 4];
            f32x4 s4 = MFMA16(kf, qf, aw0);
            float p0 = __expf(s4[0]), p1 = __expf(s4[1]);
            float p2 = __expf(s4[2]), p3 = __expf(s4[3]);
            lacc += (p0 + p1) + (p2 + p3);
            f16x4 pf;
            pf[0] = (f16)p0; pf[1] = (f16)p1; pf[2] = (f16)p2; pf[3] = (f16)p3;
            f16x4 vf = *(const f16x4*)&VTs[qr16 * 76 + kt * 16 + quad * 4];
            accO = MFMA16(vf, pf, accO);
        }
    }
    // finalize: l over quads, store o normalized as bf16
    {
        float l = lacc;
        l += __shfl_xor(l, 16);
        l += __shfl_xor(l, 32);
        float inv = 1.f / l;
        ushort4 st4;
        st4.x = f2b(accO[0] * inv);
        st4.y = f2b(accO[1] * inv);
        st4.z = f2b(accO[2] * inv);
        st4.w = f2b(accO[3] * inv);
        *(ushort4*)&ob[qrow_g * 128 + h * 16 + quad * 4] = st4;
    }
}

// -------- out = ob @ WcombTb^T + bcomb (byte-identical to R30/R33/R35) ----
__global__ __launch_bounds__(256)
void mfma_out(const u16* __restrict__ A, const u16* __restrict__ Bb,
              const float* __restrict__ bias, float* __restrict__ C) {
    const int m0 = blockIdx.x * 128;
    const int t = threadIdx.x;
    const int wave = t >> 6, lane = t & 63;
    const int wm = (wave >> 1) * 64, wn = (wave & 1) * 64;
    const int m16 = lane & 15, kq = lane >> 4;
    f32x4 acc[4][4] = {};

#pragma unroll
    for (int kc = 0; kc < 4; ++kc) {
        bf16x8 af[4], bf[4];
#pragma unroll
        for (int i = 0; i < 4; ++i)
            af[i] = *(const bf16x8*)&A[(long long)(m0 + wm + i * 16 + m16) * 128 + kc * 32 + kq * 8];
#pragma unroll
        for (int j = 0; j < 4; ++j)
            bf[j] = *(const bf16x8*)&Bb[(long long)(wn + j * 16 + m16) * 128 + kc * 32 + kq * 8];
#pragma unroll
        for (int i = 0; i < 4; ++i)
#pragma unroll
            for (int j = 0; j < 4; ++j)
                acc[i][j] = MFMAB(af[i], bf[j], acc[i][j]);
    }
#pragma unroll
    for (int i = 0; i < 4; ++i) {
#pragma unroll
        for (int r = 0; r < 4; ++r) {
            long long row = m0 + wm + i * 16 + kq * 4 + r;
#pragma unroll
            for (int j = 0; j < 4; ++j) {
                int col = wn + j * 16 + m16;
                C[row * 128 + col] = acc[i][j][r] + bias[col];
            }
        }
    }
}

extern "C" void kernel_launch(void* const* d_in, const int* in_sizes, int n_in,
                              void* d_out, int out_size, void* d_ws, size_t ws_size,
                              hipStream_t stream) {
    (void)in_sizes; (void)n_in; (void)out_size; (void)ws_size;
    const float* H    = (const float*)d_in[0];
    const float* Aadj = (const float*)d_in[1];
    const float* Wlin = (const float*)d_in[2];
    const float* blin = (const float*)d_in[3];
    const float* Win  = (const float*)d_in[4];
    const float* bin  = (const float*)d_in[5];
    const float* Wout = (const float*)d_in[6];
    const float* bout = (const float*)d_in[7];
    const float* Wfin = (const float*)d_in[8];
    const float* bfin = (const float*)d_in[9];
    float* out = (float*)d_out;
    char* ws = (char*)d_ws;

    u16*   WinTb   = (u16*)(ws + 0);          // 96 KB bf16
    u16*   WcombTb = (u16*)(ws + 98304);      // 32 KB bf16
    float* bcomb   = (float*)(ws + 131072);   // 512 B
    float* rowsum  = (float*)(ws + 131584);   // 32 KB
    u16*   Hpb     = (u16*)(ws + 262144);     // 2 MB bf16
    f16*   qkv     = (f16*)(ws + 2359296);    // 6 MB (q f16*0.25 | k f16 | v f16)
    u16*   ob      = (u16*)(ws + 8650752);    // 2 MB bf16 normalized o
    u16*   ez      = (u16*)(ws + 12845056);   // 16 MB bf16 exp(z)
    // total ~29 MB

    // prep: Hp MFMA (64 blocks) + weight transposes/combine (320 blocks)
    prep_hp<<<384, 256, 0, stream>>>(H, Wlin, Win, Wout, Wfin, bout, bfin,
                                     blin, WinTb, WcombTb, bcomb, rowsum, Hpb);
    // merged: ez-gate (512 blocks, XCD-swizzled by batch) + qkv f16 (192)
    mfma_qkvz<<<704, 256, 0, stream>>>(Hpb, WinTb, bin, qkv, Aadj, ez, rowsum);
    // flash: 1 head/block, 1024 blocks = 4 blk/CU, XCD-swizzled
    flash_mfma<<<1024, 256, 0, stream>>>(qkv, ez, rowsum, ob);
    // out = ob @ WcombTb^T + bcomb  (MFMA)
    mfma_out<<<64, 256, 0, stream>>>(ob, WcombTb, bcomb, out);
}

// Round 12
// 152.577 us; speedup vs baseline: 1.1717x; 1.0185x over previous
//
#include <hip/hip_runtime.h>
#include <hip/hip_bf16.h>

// GraphAttentionLayer: B=8,N=1024,FIN=E=OUT=128,NH=8,HD=16. f32 in/out.
// R37: vs R36 (155.40us, best): ez-section gate rebuilt as ballot-bitmask.
// Old epilogue: 64 scalar HBM Aadj loads/thread at point-of-use (4x64B
// transactions/wave, ~900cy chains under exp/stores). New: phase-0 per-wave
// coalesced stream (256B/inst, 8 loads in flight) -> __ballot(v!=0) -> 2KB
// LDS bitmask; GEMM hides the tail; epilogue tests a bit (LDS broadcast,
// free). Gate boolean identical -> bit-identical output; absmax must stay
// exactly 9.155273e-05. prep/flash/out byte-identical to R36.

using u16 = unsigned short;
typedef short bf16x8 __attribute__((ext_vector_type(8)));
typedef float f32x4 __attribute__((ext_vector_type(4)));
typedef _Float16 f16;
typedef _Float16 f16x4 __attribute__((ext_vector_type(4)));

#define MFMA16(a, b, c) __builtin_amdgcn_mfma_f32_16x16x16f16(a, b, c, 0, 0, 0)
#define MFMAB(a, b, c) __builtin_amdgcn_mfma_f32_16x16x32_bf16(a, b, c, 0, 0, 0)

__device__ __forceinline__ u16 f2b(float f) {
    unsigned u = __float_as_uint(f);
    return (u16)((u + 0x7fffu + ((u >> 16) & 1u)) >> 16);  // RNE
}
__device__ __forceinline__ float b2f(u16 u) {
    return __uint_as_float(((unsigned)u) << 16);
}

// ---- merged prep + Hp-GEMM (byte-identical to R36) ----
__global__ void prep_hp(const float* __restrict__ H, const float* __restrict__ Wlin,
                        const float* __restrict__ Win,
                        const float* __restrict__ Wout, const float* __restrict__ Wfin,
                        const float* __restrict__ bout, const float* __restrict__ bfin,
                        const float* __restrict__ blin,
                        u16* __restrict__ WinTb, u16* __restrict__ WcombTb,
                        float* __restrict__ bcomb, float* __restrict__ rowsum,
                        u16* __restrict__ Hpb) {
    if (blockIdx.x < 64) {
        const int m0 = blockIdx.x * 128;
        const int t = threadIdx.x;
        const int wave = t >> 6, lane = t & 63;
        const int wm = (wave >> 1) * 64, wn = (wave & 1) * 64;
        const int m16 = lane & 15, kq = lane >> 4;
        f32x4 acc[4][4] = {};

#pragma unroll
        for (int kc = 0; kc < 4; ++kc) {
            bf16x8 af[4], bf[4];
#pragma unroll
            for (int i = 0; i < 4; ++i) {
                const float* ap = &H[(long long)(m0 + wm + i * 16 + m16) * 128 + kc * 32 + kq * 8];
                float4 u0 = *(const float4*)ap;
                float4 u1 = *(const float4*)(ap + 4);
                bf16x8 a;
                a[0] = (short)f2b(u0.x); a[1] = (short)f2b(u0.y);
                a[2] = (short)f2b(u0.z); a[3] = (short)f2b(u0.w);
                a[4] = (short)f2b(u1.x); a[5] = (short)f2b(u1.y);
                a[6] = (short)f2b(u1.z); a[7] = (short)f2b(u1.w);
                af[i] = a;
            }
#pragma unroll
            for (int j = 0; j < 4; ++j) {
                const int col = wn + j * 16 + m16;
                const int k0 = kc * 32 + kq * 8;
                bf16x8 bb;
#pragma unroll
                for (int e = 0; e < 8; ++e)
                    bb[e] = (short)f2b(Wlin[(long long)(k0 + e) * 128 + col]);
                bf[j] = bb;
            }
#pragma unroll
            for (int i = 0; i < 4; ++i)
#pragma unroll
                for (int j = 0; j < 4; ++j)
                    acc[i][j] = MFMAB(af[i], bf[j], acc[i][j]);
        }
#pragma unroll
        for (int i = 0; i < 4; ++i) {
#pragma unroll
            for (int r = 0; r < 4; ++r) {
                long long row = m0 + wm + i * 16 + kq * 4 + r;
#pragma unroll
                for (int j = 0; j < 4; ++j) {
                    int col = wn + j * 16 + m16;
                    Hpb[row * 128 + col] = f2b(acc[i][j][r] + blin[col]);
                }
            }
        }
        return;
    }
    int i = (blockIdx.x - 64) * 256 + threadIdx.x;   // 0..81919
    if (i < 8192) rowsum[i] = 0.f;
    if (i >= 16384 && i < 65536) {
        int k = i - 16384;                    // Win 128x384 -> WinTb 384x128 bf16
        int r = k / 384, c = k - r * 384;
        WinTb[c * 128 + r] = f2b(Win[k]);
    } else if (i >= 65536) {
        int k = i - 65536;
        int o = k & 127, e = k >> 7;          // o fastest: Wfin coalesced
        float s = 0.f;
        for (int kk = 0; kk < 128; ++kk)
            s = fmaf(Wout[e * 128 + kk], Wfin[kk * 128 + o], s);
        WcombTb[o * 128 + e] = f2b(s);
        if (e == 0) {
            float sb = bfin[o];
            for (int kk = 0; kk < 128; ++kk)
                sb = fmaf(bout[kk], Wfin[kk * 128 + o], sb);
            bcomb[o] = sb;
        }
    }
}

// ---- merged qkvz: ez gate via phase-0 ballot bitmask (R37) ----
__global__ __launch_bounds__(256)
void mfma_qkvz(const u16* __restrict__ Hpb, const u16* __restrict__ WinTb,
               const float* __restrict__ bin, f16* __restrict__ Cq,
               const float* __restrict__ Aadj, u16* __restrict__ EZ,
               float* __restrict__ rowsum) {
    const int blk = blockIdx.x;
    const int t = threadIdx.x;
    const int wave = t >> 6, lane = t & 63;
    const int wm = (wave >> 1) * 64, wn = (wave & 1) * 64;
    const int m16 = lane & 15, kq = lane >> 4;
    f32x4 acc[4][4] = {};

    __shared__ unsigned long long Ms[128][2];   // 2KB gate bitmask (ez path)

    if (blk < 512) {
        // XCD swizzle: batch = blk&7 -> one batch's tiles share one XCD L2.
        const int b = blk & 7, tile = blk >> 3;
        const int mt = tile >> 3, nt = tile & 7;
        const u16* Ab = Hpb + (long long)b * 1024 * 128;
        const int m0 = mt * 128, n0 = nt * 128;
        const long long zb = (long long)b * 1024 * 1024;

        // phase 0: gate bitmask. wave w streams rows w*32..w*32+31, two
        // 64-col halves each: coalesced 256B/wave loads, ballot-packed.
        {
            const long long abase = zb + (long long)m0 * 1024 + n0 + lane;
#pragma unroll
            for (int c = 0; c < 8; ++c) {
                float vv[8];
#pragma unroll
                for (int u = 0; u < 8; ++u) {
                    int it = c * 8 + u;
                    int rowl = wave * 32 + (it >> 1);
                    int half = it & 1;
                    vv[u] = Aadj[abase + (long long)rowl * 1024 + (half << 6)];
                }
#pragma unroll
                for (int u = 0; u < 8; ++u) {
                    int it = c * 8 + u;
                    unsigned long long mm = __ballot(vv[u] != 0.f);
                    if (lane == 0) Ms[wave * 32 + (it >> 1)][it & 1] = mm;
                }
            }
        }

#pragma unroll
        for (int kc = 0; kc < 4; ++kc) {
            bf16x8 af[4], bf[4];
#pragma unroll
            for (int i = 0; i < 4; ++i)
                af[i] = *(const bf16x8*)&Ab[(long long)(m0 + wm + i * 16 + m16) * 128 + kc * 32 + kq * 8];
#pragma unroll
            for (int j = 0; j < 4; ++j)
                bf[j] = *(const bf16x8*)&Ab[(long long)(n0 + wn + j * 16 + m16) * 128 + kc * 32 + kq * 8];
#pragma unroll
            for (int i = 0; i < 4; ++i)
#pragma unroll
                for (int j = 0; j < 4; ++j)
                    acc[i][j] = MFMAB(af[i], bf[j], acc[i][j]);
        }
        __syncthreads();   // Ms complete (GEMM hid the load tail)
#pragma unroll
        for (int i = 0; i < 4; ++i) {
#pragma unroll
            for (int r = 0; r < 4; ++r) {
                int rowl = wm + i * 16 + kq * 4 + r;
                int row = m0 + rowl;
                float es = 0.f;
#pragma unroll
                for (int j = 0; j < 4; ++j) {
                    int coll = wn + j * 16 + m16;
                    int col = n0 + coll;
                    float v = acc[i][j][r];
                    v = v >= 0.f ? v : 0.2f * v;                    // LeakyReLU(0.2)
                    if (!((Ms[rowl][coll >> 6] >> (coll & 63)) & 1ull)) v = 0.f;  // gate
                    float ev = __expf(v);                           // m=0: |z| bounded
                    EZ[zb + (long long)row * 1024 + col] = f2b(ev);
                    es += ev;
                }
#pragma unroll
                for (int off = 1; off < 16; off <<= 1) es += __shfl_xor(es, off);
                if (m16 == 0) atomicAdd(&rowsum[b * 1024 + row], es);
            }
        }
    } else {
        const int q = blk - 512;
        const int mt = q & 63, slab = q >> 6;   // 0=q, 1=k, 2=v
        const int m0 = mt * 128;
        const u16* Bslab = WinTb + (long long)slab * 128 * 128;
#pragma unroll
        for (int kc = 0; kc < 4; ++kc) {
            bf16x8 af[4], bf[4];
#pragma unroll
            for (int i = 0; i < 4; ++i)
                af[i] = *(const bf16x8*)&Hpb[(long long)(m0 + wm + i * 16 + m16) * 128 + kc * 32 + kq * 8];
#pragma unroll
            for (int j = 0; j < 4; ++j)
                bf[j] = *(const bf16x8*)&Bslab[(long long)(wn + j * 16 + m16) * 128 + kc * 32 + kq * 8];
#pragma unroll
            for (int i = 0; i < 4; ++i)
#pragma unroll
                for (int j = 0; j < 4; ++j)
                    acc[i][j] = MFMAB(af[i], bf[j], acc[i][j]);
        }
        const float qscale = (slab == 0) ? 0.25f : 1.f;   // fold 1/sqrt(HD) into q
#pragma unroll
        for (int i = 0; i < 4; ++i) {
#pragma unroll
            for (int r = 0; r < 4; ++r) {
                long long row = m0 + wm + i * 16 + kq * 4 + r;
#pragma unroll
                for (int j = 0; j < 4; ++j) {
                    int col = wn + j * 16 + m16;
                    float v = (acc[i][j][r] + bin[slab * 128 + col]) * qscale;
                    Cq[row * 384 + slab * 128 + col] = (f16)v;
                }
            }
        }
    }
}

// ---- flash (byte-identical to R36: 1 head/block, 1024 blocks, XCD swz) ----
__global__ __launch_bounds__(256)
void flash_mfma(const f16* __restrict__ qkv, const u16* __restrict__ ez,
                const float* __restrict__ rowsum, u16* __restrict__ ob) {
    const int bid = blockIdx.x;
    const int xcd = bid & 7;
    const int rr_ = bid >> 3;
    const int h = rr_ & 7;               // head 0..7
    const int g = rr_ >> 3;              // 0..15
    const int pair = g * 8 + xcd;        // 0..127 = (b, qblk)
    const int n0 = (pair & 15) * 64;     // qblk
    const int b = pair >> 4;             // batch
    const int t = threadIdx.x;
    const int w = t >> 6, lane = t & 63;
    const int qr16 = lane & 15, quad = lane >> 4;

    __shared__ u16 Ks[64 * 24];    // [key][dim 0..15 of head], stride 24
    __shared__ u16 VTs[16 * 76];   // [dim 0..15][key], stride 76 (bank-safe)
    __shared__ u16 AWs[64 * 72];   // [qrow 0..63][key 0..63] bf16 (ez)

    const int qrow_l = w * 16 + qr16;                 // block-local qrow
    const long long qrow_g = b * 1024 + n0 + qrow_l;  // global qrow
    const float inv0 = 1.f / rowsum[qrow_g];

    f16x4 qf = *(const f16x4*)&qkv[qrow_g * 384 + h * 16 + quad * 4];

    f32x4 accO = {};
    float lacc = 0.f;

    for (int st = 0; st < 16; ++st) {
        const int kb = st * 64;
        __syncthreads();
        // stage K (64 keys x 16 dims) uint2: key = t>>2, c4 = t&3
        {
            const int key = t >> 2, c4 = t & 3;
            const long long kr = ((long long)(b * 1024 + kb + key)) * 384;
            *(uint2*)&Ks[key * 24 + c4 * 4] =
                *(const uint2*)&qkv[kr + 128 + h * 16 + c4 * 4];
            // stage V transposed: VTs[dim][key]
            f16x4 v0;
            *(uint2*)&v0 = *(const uint2*)&qkv[kr + 256 + h * 16 + c4 * 4];
            const int d0 = c4 * 4;
#pragma unroll
            for (int i = 0; i < 4; ++i)
                VTs[(d0 + i) * 76 + key] = ((const u16*)&v0)[i];
        }
        // stage AW (64 qrows x 64 keys) b128
#pragma unroll
        for (int rr2 = 0; rr2 < 2; ++rr2) {
            int idx = rr2 * 256 + t;
            int row = idx >> 3, c16 = idx & 7;
            *(uint4*)&AWs[row * 72 + c16 * 8] =
                *(const uint4*)&ez[((long long)(b * 1024 + n0 + row)) * 1024 + kb + c16 * 8];
        }
        __syncthreads();

#pragma unroll 2
        for (int kt = 0; kt < 4; ++kt) {
            // aw C-init: lane holds (qrow=qr16, keys kt*16+quad*4+r)
            ushort4 ue = *(const ushort4*)&AWs[qrow_l * 72 + kt * 16 + quad * 4];
            f32x4 aw0;
            aw0[0] = b2f(ue.x) * inv0; aw0[1] = b2f(ue.y) * inv0;
            aw0[2] = b2f(ue.z) * inv0; aw0[3] = b2f(ue.w) * inv0;
            f16x4 kf = *(const f16x4*)&Ks[(kt * 16 + qr16) * 24 + quad * 4];
            f32x4 s4 = MFMA16(kf, qf, aw0);
            float p0 = __expf(s4[0]), p1 = __expf(s4[1]);
            float p2 = __expf(s4[2]), p3 = __expf(s4[3]);
            lacc += (p0 + p1) + (p2 + p3);
            f16x4 pf;
            pf[0] = (f16)p0; pf[1] = (f16)p1; pf[2] = (f16)p2; pf[3] = (f16)p3;
            f16x4 vf = *(const f16x4*)&VTs[qr16 * 76 + kt * 16 + quad * 4];
            accO = MFMA16(vf, pf, accO);
        }
    }
    // finalize: l over quads, store o normalized as bf16
    {
        float l = lacc;
        l += __shfl_xor(l, 16);
        l += __shfl_xor(l, 32);
        float inv = 1.f / l;
        ushort4 st4;
        st4.x = f2b(accO[0] * inv);
        st4.y = f2b(accO[1] * inv);
        st4.z = f2b(accO[2] * inv);
        st4.w = f2b(accO[3] * inv);
        *(ushort4*)&ob[qrow_g * 128 + h * 16 + quad * 4] = st4;
    }
}

// -------- out = ob @ WcombTb^T + bcomb (byte-identical to R36) --------
__global__ __launch_bounds__(256)
void mfma_out(const u16* __restrict__ A, const u16* __restrict__ Bb,
              const float* __restrict__ bias, float* __restrict__ C) {
    const int m0 = blockIdx.x * 128;
    const int t = threadIdx.x;
    const int wave = t >> 6, lane = t & 63;
    const int wm = (wave >> 1) * 64, wn = (wave & 1) * 64;
    const int m16 = lane & 15, kq = lane >> 4;
    f32x4 acc[4][4] = {};

#pragma unroll
    for (int kc = 0; kc < 4; ++kc) {
        bf16x8 af[4], bf[4];
#pragma unroll
        for (int i = 0; i < 4; ++i)
            af[i] = *(const bf16x8*)&A[(long long)(m0 + wm + i * 16 + m16) * 128 + kc * 32 + kq * 8];
#pragma unroll
        for (int j = 0; j < 4; ++j)
            bf[j] = *(const bf16x8*)&Bb[(long long)(wn + j * 16 + m16) * 128 + kc * 32 + kq * 8];
#pragma unroll
        for (int i = 0; i < 4; ++i)
#pragma unroll
            for (int j = 0; j < 4; ++j)
                acc[i][j] = MFMAB(af[i], bf[j], acc[i][j]);
    }
#pragma unroll
    for (int i = 0; i < 4; ++i) {
#pragma unroll
        for (int r = 0; r < 4; ++r) {
            long long row = m0 + wm + i * 16 + kq * 4 + r;
#pragma unroll
            for (int j = 0; j < 4; ++j) {
                int col = wn + j * 16 + m16;
                C[row * 128 + col] = acc[i][j][r] + bias[col];
            }
        }
    }
}

extern "C" void kernel_launch(void* const* d_in, const int* in_sizes, int n_in,
                              void* d_out, int out_size, void* d_ws, size_t ws_size,
                              hipStream_t stream) {
    (void)in_sizes; (void)n_in; (void)out_size; (void)ws_size;
    const float* H    = (const float*)d_in[0];
    const float* Aadj = (const float*)d_in[1];
    const float* Wlin = (const float*)d_in[2];
    const float* blin = (const float*)d_in[3];
    const float* Win  = (const float*)d_in[4];
    const float* bin  = (const float*)d_in[5];
    const float* Wout = (const float*)d_in[6];
    const float* bout = (const float*)d_in[7];
    const float* Wfin = (const float*)d_in[8];
    const float* bfin = (const float*)d_in[9];
    float* out = (float*)d_out;
    char* ws = (char*)d_ws;

    u16*   WinTb   = (u16*)(ws + 0);          // 96 KB bf16
    u16*   WcombTb = (u16*)(ws + 98304);      // 32 KB bf16
    float* bcomb   = (float*)(ws + 131072);   // 512 B
    float* rowsum  = (float*)(ws + 131584);   // 32 KB
    u16*   Hpb     = (u16*)(ws + 262144);     // 2 MB bf16
    f16*   qkv     = (f16*)(ws + 2359296);    // 6 MB (q f16*0.25 | k f16 | v f16)
    u16*   ob      = (u16*)(ws + 8650752);    // 2 MB bf16 normalized o
    u16*   ez      = (u16*)(ws + 12845056);   // 16 MB bf16 exp(z)
    // total ~29 MB

    // prep: Hp MFMA (64 blocks) + weight transposes/combine (320 blocks)
    prep_hp<<<384, 256, 0, stream>>>(H, Wlin, Win, Wout, Wfin, bout, bfin,
                                     blin, WinTb, WcombTb, bcomb, rowsum, Hpb);
    // merged: ez-gate (512 blocks, ballot-bitmask gate) + qkv f16 (192)
    mfma_qkvz<<<704, 256, 0, stream>>>(Hpb, WinTb, bin, qkv, Aadj, ez, rowsum);
    // flash: 1 head/block, 1024 blocks = 4 blk/CU, XCD-swizzled
    flash_mfma<<<1024, 256, 0, stream>>>(qkv, ez, rowsum, ob);
    // out = ob @ WcombTb^T + bcomb  (MFMA)
    mfma_out<<<64, 256, 0, stream>>>(ob, WcombTb, bcomb, out);
}